// Round 9
// baseline (75.421 us; speedup 1.0000x reference)
//
#include <hip/hip_runtime.h>
#include <hip/hip_bf16.h>

#define N_ROWS 8192
#define D_DIM  1024           // elements per row
#define ROWB   512            // fp4 row bytes (1024 elems * 0.5B)
#define DELTA  0.1f
#define EPSF   1e-8f

#define BM 256
#define BN 256
#define BKB 64                // K-tile row bytes = 128 fp4 elems
#define NT (ROWB / BKB)       // 8 K-tiles

typedef __attribute__((ext_vector_type(4))) int    i32x4;
typedef __attribute__((ext_vector_type(8))) int    i32x8;
typedef __attribute__((ext_vector_type(16))) float f32x16;

// Software fp4 (e2m1) encode of v*32, RNE-by-midpoints, clamp at 6.
__device__ inline unsigned int fp4_enc(float v) {
    const unsigned int s = (__float_as_uint(v) >> 31) & 1u;
    float m = fminf(fabsf(v) * 32.0f, 6.0f);
    unsigned int c = 0;
    c += (m >= 0.25f); c += (m >= 0.75f); c += (m >= 1.25f); c += (m >= 1.75f);
    c += (m >= 2.5f);  c += (m >= 3.5f);  c += (m >= 5.0f);
    return (s << 3) | c;
}

// One block per row: compute xx, yy, xy; write normalized fp4 rows (x32) + fp32 pos.
__global__ __launch_bounds__(256) void norm_kernel(
    const float* __restrict__ X, const float* __restrict__ Y,
    unsigned short* __restrict__ Xn, unsigned short* __restrict__ Yn,  // [8192][256] u16
    float* __restrict__ pos)
{
    const int row = blockIdx.x;
    const int t = threadIdx.x;            // 256 threads, 4 f32 each = 1024
    const float4 xv = reinterpret_cast<const float4*>(X + (size_t)row * D_DIM)[t];
    const float4 yv = reinterpret_cast<const float4*>(Y + (size_t)row * D_DIM)[t];

    float xx = xv.x*xv.x + xv.y*xv.y + xv.z*xv.z + xv.w*xv.w;
    float yy = yv.x*yv.x + yv.y*yv.y + yv.z*yv.z + yv.w*yv.w;
    float xy = xv.x*yv.x + xv.y*yv.y + xv.z*yv.z + xv.w*yv.w;

    #pragma unroll
    for (int off = 32; off > 0; off >>= 1) {
        xx += __shfl_xor(xx, off);
        yy += __shfl_xor(yy, off);
        xy += __shfl_xor(xy, off);
    }
    __shared__ float red[12];
    const int wid = t >> 6, lane = t & 63;
    if (lane == 0) { red[wid] = xx; red[4 + wid] = yy; red[8 + wid] = xy; }
    __syncthreads();
    xx = red[0] + red[1] + red[2] + red[3];
    yy = red[4] + red[5] + red[6] + red[7];
    xy = red[8] + red[9] + red[10] + red[11];

    const float rnx = 1.0f / fmaxf(sqrtf(xx), EPSF);
    const float rny = 1.0f / fmaxf(sqrtf(yy), EPSF);
    if (t == 0) pos[row] = xy * rnx * rny;

    // 4 fp4 nibbles -> one u16, K ascending low-to-high (identical for X and Y)
    const unsigned int px = fp4_enc(xv.x * rnx) | (fp4_enc(xv.y * rnx) << 4)
                          | (fp4_enc(xv.z * rnx) << 8) | (fp4_enc(xv.w * rnx) << 12);
    const unsigned int py = fp4_enc(yv.x * rny) | (fp4_enc(yv.y * rny) << 4)
                          | (fp4_enc(yv.z * rny) << 8) | (fp4_enc(yv.w * rny) << 12);
    Xn[(size_t)row * 256 + t] = (unsigned short)px;
    Yn[(size_t)row * 256 + t] = (unsigned short)py;
}

#define GLDS16(gptr, lptr) \
    __builtin_amdgcn_global_load_lds((const __attribute__((address_space(1))) void*)(gptr), \
                                     (__attribute__((address_space(3))) void*)(lptr), 16, 0, 0)

// Swizzled 16B-chunk read: logical chunk lc of row -> physical chunk lc^(row&3).
__device__ inline i32x8 ldfrag16s(const unsigned char* base, int row, int lc) {
    const int pc = lc ^ (row & 3);
    const i32x4 u = *reinterpret_cast<const i32x4*>(base + row * BKB + pc * 16);
    i32x8 r;
    r[0] = u[0]; r[1] = u[1]; r[2] = u[2]; r[3] = u[3];
    r[4] = 0; r[5] = 0; r[6] = 0; r[7] = 0;   // fp4 uses low 4 regs only
    return r;
}

// One 1KB staging unit (16 rows x 64B): lane -> row j*16+(lane>>2), phys chunk
// lane&3. LDS dest linear (gload_lds rule); swizzle pre-applied to the GLOBAL
// source chunk so LDS[row][p] = G[row][p ^ (row&3)].
#define STAGE1(dst, gbase, kkb, j) { \
    const unsigned char* g_ = (gbase) + (size_t)((j) * 16 + srow) * ROWB + (kkb) + schunk * 16; \
    GLDS16(g_, (dst) + (j) * 1024); }

// Stage one 256x64B panel (16 KB): 2 units/thread (wave wv takes j = wv, 8+wv).
#define STAGE_P(dst, gbase, kkb) { \
    STAGE1(dst, gbase, kkb, wv); STAGE1(dst, gbase, kkb, 8 + wv); }

// Per-instr-K fragment loads (32x32x64: lane&31 = row/col, lane>>5 = K-half)
#define LOAD_K(k) { \
    _Pragma("unroll") for (int mi = 0; mi < 4; ++mi) { \
        const int r_ = wm * 128 + mi * 32 + (lane & 31); \
        af[mi] = ldfrag16s(a, r_, (k) * 2 + (lane >> 5)); } \
    _Pragma("unroll") for (int nj = 0; nj < 2; ++nj) { \
        const int c_ = wn * 64 + nj * 32 + (lane & 31); \
        bfv[nj] = ldfrag16s(b, c_, (k) * 2 + (lane >> 5)); } }

// 8 mfma_scale (4 mi x 2 nj); cbsz=4/blgp=4 = fp4 e2m1; unit scales (0x7F = 1.0)
#define MFMA_K() { _Pragma("unroll") for (int mi = 0; mi < 4; ++mi) { \
    _Pragma("unroll") for (int nj = 0; nj < 2; ++nj) { \
        acc[mi][nj] = __builtin_amdgcn_mfma_scale_f32_32x32x64_f8f6f4( \
            af[mi], bfv[nj], acc[mi][nj], 4, 4, 0, 0x7F7F7F7F, 0, 0x7F7F7F7F); } } }

// S*1024 = (32Xn)*(32Yn)^T 256x256 fp4 tile; 3-buffer LDS ring, ONE barrier +
// ONE counted vmcnt per K-tile (no mid-tile drain); 32x32x64 MFMA; hinge+sum.
__global__ __launch_bounds__(512, 2) void gemm_loss_kernel(
    const unsigned char* __restrict__ A,   // Xn [N][512B] fp4
    const unsigned char* __restrict__ B,   // Yn [N][512B] fp4
    const float* __restrict__ pos,
    float* __restrict__ out)
{
    __shared__ __align__(16) unsigned char sA[3][BM * BKB];  // 48 KB
    __shared__ __align__(16) unsigned char sB[3][BN * BKB];  // 48 KB
    __shared__ float sPos[BM];
    __shared__ float redW[8];

    // XCD-aware swizzle (1024 blocks, 1024 % 8 == 0 -> bijective)
    const int nwg = gridDim.x;
    const int bid = blockIdx.x;
    const int cpx = nwg >> 3;
    const int swz = (bid & 7) * cpx + (bid >> 3);
    const int row0 = (swz >> 5) * BM;   // 32 tiles per dim
    const int col0 = (swz & 31) * BN;

    const int tid = threadIdx.x;
    const int lane = tid & 63;
    const int wv = tid >> 6;         // 8 waves: 2M x 4N
    const int wm = wv >> 2;          // rows [wm*128, +128)
    const int wn = wv & 3;           // cols [wn*64, +64)

    const int srow = lane >> 2;                     // 0..15
    const int schunk = (lane & 3) ^ (srow & 3);     // pre-swizzled global chunk
    const unsigned char* Ab = A + (size_t)row0 * ROWB;
    const unsigned char* Bb = B + (size_t)col0 * ROWB;

    f32x16 acc[4][2] = {};
    i32x8 af[4], bfv[2];

    // prologue: stage tiles 0 and 1 (8 stage loads/thread in flight)
    STAGE_P(&sA[0][0], Ab, 0);
    STAGE_P(&sB[0][0], Bb, 0);
    STAGE_P(&sA[1][0], Ab, BKB);
    STAGE_P(&sB[1][0], Bb, BKB);

    #pragma unroll
    for (int kt = 0; kt < NT; ++kt) {
        // boundary: tile kt's 4 loads (oldest) complete; kt+1's stay in flight
        if (kt == NT - 1) { asm volatile("s_waitcnt vmcnt(0)" ::: "memory"); }
        else              { asm volatile("s_waitcnt vmcnt(4)" ::: "memory"); }
        __builtin_amdgcn_s_barrier();
        __builtin_amdgcn_sched_barrier(0);

        const unsigned char* a = &sA[kt % 3][0];
        const unsigned char* b = &sB[kt % 3][0];

        // stage tile kt+2 into buf[(kt+2)%3] = buf[(kt-1)%3]: all reads of it
        // retired before this tile's barrier (lgkm-waited by consuming MFMAs)
        if (kt + 2 < NT) {
            STAGE_P(&sA[(kt + 2) % 3][0], Ab, (kt + 2) * BKB);
            STAGE_P(&sB[(kt + 2) % 3][0], Bb, (kt + 2) * BKB);
        }
        __builtin_amdgcn_sched_barrier(0);

        LOAD_K(0);
        __builtin_amdgcn_s_setprio(1);
        MFMA_K();
        __builtin_amdgcn_s_setprio(0);
        LOAD_K(1);
        __builtin_amdgcn_s_setprio(1);
        MFMA_K();
        __builtin_amdgcn_s_setprio(0);
    }

    // pos staged after the K-loop (keeps in-loop vmcnt accounting pure)
    if (tid < BM) sPos[tid] = pos[row0 + tid];
    __syncthreads();

    // epilogue: hinge = max(0, DELTA - pos[i] + S[i][j]); S = acc/1024.
    // 32x32 C/D map: col = lane&31, row = (reg&3) + 8*(reg>>2) + 4*(lane>>5)
    const float inv = 1.0f / 1024.0f;
    const int rbase = 4 * (lane >> 5);
    float local = 0.0f;
    #pragma unroll
    for (int mi = 0; mi < 4; ++mi) {
        #pragma unroll
        for (int rg = 0; rg < 16; ++rg) {
            const int lr = wm * 128 + mi * 32 + (rg & 3) + 8 * (rg >> 2) + rbase;
            const int gr = row0 + lr;
            const float basev = DELTA - sPos[lr];
            #pragma unroll
            for (int nj = 0; nj < 2; ++nj) {
                const int gc = col0 + wn * 64 + nj * 32 + (lane & 31);
                float h = basev + acc[mi][nj][rg] * inv;
                h = fmaxf(h, 0.0f);
                if (gr == gc) h = 0.0f;
                local += h;
            }
        }
    }
    #pragma unroll
    for (int off = 32; off > 0; off >>= 1) local += __shfl_xor(local, off);
    if (lane == 0) redW[wv] = local;
    __syncthreads();
    if (tid == 0) {
        float s = 0.0f;
        #pragma unroll
        for (int w = 0; w < 8; ++w) s += redW[w];
        atomicAdd(out, s);
    }
}

extern "C" void kernel_launch(void* const* d_in, const int* in_sizes, int n_in,
                              void* d_out, int out_size, void* d_ws, size_t ws_size,
                              hipStream_t stream) {
    const float* X = (const float*)d_in[0];
    const float* Y = (const float*)d_in[1];
    float* out = (float*)d_out;

    unsigned char* Xn = (unsigned char*)d_ws;                        // 4 MB fp4
    unsigned char* Yn = Xn + (size_t)N_ROWS * ROWB;                  // 4 MB fp4
    float* pos = (float*)(Yn + (size_t)N_ROWS * ROWB);               // 32 KB

    hipMemsetAsync(d_out, 0, sizeof(float), stream);
    norm_kernel<<<N_ROWS, 256, 0, stream>>>(X, Y, (unsigned short*)Xn, (unsigned short*)Yn, pos);
    const int ntiles = (N_ROWS / BM) * (N_ROWS / BN);   // 1024
    gemm_loss_kernel<<<dim3(ntiles), 512, 0, stream>>>(Xn, Yn, pos, out);
}

// Round 10
// 67.817 us; speedup vs baseline: 1.1121x; 1.1121x over previous
//
#include <hip/hip_runtime.h>
#include <hip/hip_bf16.h>

#define N_ROWS 8192
#define D_DIM  1024           // elements per row
#define ROWB   512            // fp4 row bytes (1024 elems * 0.5B)
#define DELTA  0.1f
#define EPSF   1e-8f

#define BM 256
#define BN 256
#define BKB 128               // K-tile row bytes = 256 fp4 elems
#define NT (ROWB / BKB)       // 4 K-tiles

typedef __attribute__((ext_vector_type(4))) int   i32x4;
typedef __attribute__((ext_vector_type(8))) int   i32x8;
typedef __attribute__((ext_vector_type(4))) float f32x4;

// Software fp4 (e2m1) encode of v*32, RNE-by-midpoints, clamp at 6.
__device__ inline unsigned int fp4_enc(float v) {
    const unsigned int s = (__float_as_uint(v) >> 31) & 1u;
    float m = fminf(fabsf(v) * 32.0f, 6.0f);
    unsigned int c = 0;
    c += (m >= 0.25f); c += (m >= 0.75f); c += (m >= 1.25f); c += (m >= 1.75f);
    c += (m >= 2.5f);  c += (m >= 3.5f);  c += (m >= 5.0f);
    return (s << 3) | c;
}

// One block per row: compute xx, yy, xy; write normalized fp4 rows (x32) + fp32 pos.
__global__ __launch_bounds__(256) void norm_kernel(
    const float* __restrict__ X, const float* __restrict__ Y,
    unsigned short* __restrict__ Xn, unsigned short* __restrict__ Yn,  // [8192][256] u16
    float* __restrict__ pos)
{
    const int row = blockIdx.x;
    const int t = threadIdx.x;            // 256 threads, 4 f32 each = 1024
    const float4 xv = reinterpret_cast<const float4*>(X + (size_t)row * D_DIM)[t];
    const float4 yv = reinterpret_cast<const float4*>(Y + (size_t)row * D_DIM)[t];

    float xx = xv.x*xv.x + xv.y*xv.y + xv.z*xv.z + xv.w*xv.w;
    float yy = yv.x*yv.x + yv.y*yv.y + yv.z*yv.z + yv.w*yv.w;
    float xy = xv.x*yv.x + xv.y*yv.y + xv.z*yv.z + xv.w*yv.w;

    #pragma unroll
    for (int off = 32; off > 0; off >>= 1) {
        xx += __shfl_xor(xx, off);
        yy += __shfl_xor(yy, off);
        xy += __shfl_xor(xy, off);
    }
    __shared__ float red[12];
    const int wid = t >> 6, lane = t & 63;
    if (lane == 0) { red[wid] = xx; red[4 + wid] = yy; red[8 + wid] = xy; }
    __syncthreads();
    xx = red[0] + red[1] + red[2] + red[3];
    yy = red[4] + red[5] + red[6] + red[7];
    xy = red[8] + red[9] + red[10] + red[11];

    const float rnx = 1.0f / fmaxf(sqrtf(xx), EPSF);
    const float rny = 1.0f / fmaxf(sqrtf(yy), EPSF);
    if (t == 0) pos[row] = xy * rnx * rny;

    // 4 fp4 nibbles -> one u16, K ascending low-to-high (identical for X and Y)
    const unsigned int px = fp4_enc(xv.x * rnx) | (fp4_enc(xv.y * rnx) << 4)
                          | (fp4_enc(xv.z * rnx) << 8) | (fp4_enc(xv.w * rnx) << 12);
    const unsigned int py = fp4_enc(yv.x * rny) | (fp4_enc(yv.y * rny) << 4)
                          | (fp4_enc(yv.z * rny) << 8) | (fp4_enc(yv.w * rny) << 12);
    Xn[(size_t)row * 256 + t] = (unsigned short)px;
    Yn[(size_t)row * 256 + t] = (unsigned short)py;
}

#define GLDS16(gptr, lptr) \
    __builtin_amdgcn_global_load_lds((const __attribute__((address_space(1))) void*)(gptr), \
                                     (__attribute__((address_space(3))) void*)(lptr), 16, 0, 0)

// Swizzled 16B-chunk read: logical chunk lc (of 8) of row -> physical chunk
// lc^(row&7). Rows are 128B; 16 lanes sharing lc hit 8 distinct chunks ->
// 2 lanes/bank-group = conflict-free (m136).
__device__ inline i32x8 ldfrag16s(const unsigned char* base, int row, int lc) {
    const int pc = lc ^ (row & 7);
    const i32x4 u = *reinterpret_cast<const i32x4*>(base + row * BKB + pc * 16);
    i32x8 r;
    r[0] = u[0]; r[1] = u[1]; r[2] = u[2]; r[3] = u[3];
    r[4] = 0; r[5] = 0; r[6] = 0; r[7] = 0;   // fp4 uses low 4 regs only
    return r;
}

// One 1KB staging unit (8 rows x 128B): lane -> row j*8+(lane>>3), phys chunk
// lane&7. LDS dest linear (gload_lds rule); swizzle pre-applied to the GLOBAL
// source chunk so LDS[row][p] = G[row][p ^ (row&7)]  (proven zero-conflict).
#define STAGE1(dst, gbase, kkb, j) { \
    const unsigned char* g_ = (gbase) + (size_t)((j) * 8 + srow) * ROWB + (kkb) + schunk * 16; \
    GLDS16(g_, (dst) + (j) * 1024); }

// Stage one 256x128B panel (32 KB): 4 units/thread (wave wv takes j = q*8+wv).
#define STAGE_P(dst, gbase, kkb) { \
    STAGE1(dst, gbase, kkb, wv); STAGE1(dst, gbase, kkb, 8 + wv); \
    STAGE1(dst, gbase, kkb, 16 + wv); STAGE1(dst, gbase, kkb, 24 + wv); }

// Fragment loads for 16x16x128: lane -> row (lane&15), k-chunk (lane>>4);
// k-step ks selects chunks ks*4 .. ks*4+3.
#define LOAD_A_G(g, ks) { _Pragma("unroll") for (int mi = 0; mi < 4; ++mi) { \
    const int r_ = wm * 128 + ((g) * 4 + mi) * 16 + (lane & 15); \
    af[mi] = ldfrag16s(a, r_, (ks) * 4 + (lane >> 4)); } }

#define LOAD_B_ALL(ks) { _Pragma("unroll") for (int nj = 0; nj < 4; ++nj) { \
    const int c_ = wn * 64 + nj * 16 + (lane & 15); \
    bf[nj] = ldfrag16s(b, c_, (ks) * 4 + (lane >> 4)); } }

// 16 mfma_scale; cbsz=4/blgp=4 = fp4 e2m1; unit scales (0x7F = e8m0 1.0)
#define MFMA_H(g) { _Pragma("unroll") for (int mi = 0; mi < 4; ++mi) { \
    _Pragma("unroll") for (int nj = 0; nj < 4; ++nj) { \
        acc[(g)*4+mi][nj] = __builtin_amdgcn_mfma_scale_f32_16x16x128_f8f6f4( \
            af[mi], bf[nj], acc[(g)*4+mi][nj], 4, 4, 0, 0x7F7F7F7F, 0, 0x7F7F7F7F); } } }

// S*1024 = (32Xn)*(32Yn)^T 256x256 fp4 tile; BKB=128B (NT=4) counted-vmcnt
// pipeline, prefetch distance 2, in-place restage; half the barriers/drains
// of the BKB=64 version. Fused hinge + diag mask + sum.
__global__ __launch_bounds__(512, 2) void gemm_loss_kernel(
    const unsigned char* __restrict__ A,   // Xn [N][512B] fp4
    const unsigned char* __restrict__ B,   // Yn [N][512B] fp4
    const float* __restrict__ pos,
    float* __restrict__ out)
{
    __shared__ __align__(16) unsigned char sA[2][BM * BKB];  // 64 KB
    __shared__ __align__(16) unsigned char sB[2][BN * BKB];  // 64 KB
    __shared__ float sPos[BM];
    __shared__ float redW[8];

    // XCD-aware swizzle (1024 blocks, 1024 % 8 == 0 -> bijective)
    const int nwg = gridDim.x;
    const int bid = blockIdx.x;
    const int cpx = nwg >> 3;
    const int swz = (bid & 7) * cpx + (bid >> 3);
    const int row0 = (swz >> 5) * BM;   // 32 tiles per dim
    const int col0 = (swz & 31) * BN;

    const int tid = threadIdx.x;
    const int lane = tid & 63;
    const int wv = tid >> 6;         // 8 waves: 2M x 4N
    const int wm = wv >> 2;          // rows [wm*128, +128)
    const int wn = wv & 3;           // cols [wn*64, +64)

    const int srow = lane >> 3;                     // 0..7
    const int schunk = (lane & 7) ^ srow;           // pre-swizzled global chunk
    const unsigned char* Ab = A + (size_t)row0 * ROWB;
    const unsigned char* Bb = B + (size_t)col0 * ROWB;

    f32x4 acc[8][4] = {};
    i32x8 af[4], bf[4];

    // prologue: stage tiles 0 and 1 (16 stage loads/thread in flight)
    STAGE_P(&sA[0][0], Ab, 0);
    STAGE_P(&sB[0][0], Bb, 0);
    STAGE_P(&sA[1][0], Ab, BKB);
    STAGE_P(&sB[1][0], Bb, BKB);

    for (int kt = 0; kt < NT; ++kt) {
        const int c = kt & 1;
        // counted wait: tile kt's 8 loads (oldest) complete; kt+1's stay in flight
        if (kt == NT - 1) { asm volatile("s_waitcnt vmcnt(0)" ::: "memory"); }
        else              { asm volatile("s_waitcnt vmcnt(8)" ::: "memory"); }
        __builtin_amdgcn_s_barrier();
        __builtin_amdgcn_sched_barrier(0);

        const unsigned char* a = &sA[c][0];
        const unsigned char* b = &sB[c][0];

        // k-step 0
        LOAD_B_ALL(0);
        LOAD_A_G(0, 0);
        __builtin_amdgcn_s_setprio(1);
        MFMA_H(0);
        __builtin_amdgcn_s_setprio(0);
        LOAD_A_G(1, 0);
        __builtin_amdgcn_s_setprio(1);
        MFMA_H(1);
        __builtin_amdgcn_s_setprio(0);

        // k-step 1
        LOAD_B_ALL(1);
        LOAD_A_G(0, 1);
        __builtin_amdgcn_s_setprio(1);
        MFMA_H(0);
        __builtin_amdgcn_s_setprio(0);
        LOAD_A_G(1, 1);
        // all 24 reads of this buffer issued; drain + barrier, then restage
        // in place (stage deadline = boundary kt+2, two tiles away)
        asm volatile("s_waitcnt lgkmcnt(0)" ::: "memory");
        __builtin_amdgcn_s_barrier();
        __builtin_amdgcn_sched_barrier(0);
        if (kt + 2 < NT) {
            STAGE_P(&sA[c][0], Ab, (kt + 2) * BKB);
            STAGE_P(&sB[c][0], Bb, (kt + 2) * BKB);
        }
        __builtin_amdgcn_s_setprio(1);
        MFMA_H(1);
        __builtin_amdgcn_s_setprio(0);
    }

    // pos staged after the K-loop (keeps in-loop vmcnt accounting pure)
    if (tid < BM) sPos[tid] = pos[row0 + tid];
    __syncthreads();

    // epilogue: hinge = max(0, DELTA - pos[i] + S[i][j]); S = acc/1024 (x32 x32)
    const float inv = 1.0f / 1024.0f;
    float local = 0.0f;
    #pragma unroll
    for (int mi = 0; mi < 8; ++mi) {
        #pragma unroll
        for (int jj = 0; jj < 4; ++jj) {
            const int lr = wm * 128 + mi * 16 + (lane >> 4) * 4 + jj;
            const int gr = row0 + lr;
            const float basev = DELTA - sPos[lr];
            #pragma unroll
            for (int nj = 0; nj < 4; ++nj) {
                const int gc = col0 + wn * 64 + nj * 16 + (lane & 15);
                float h = basev + acc[mi][nj][jj] * inv;
                h = fmaxf(h, 0.0f);
                if (gr == gc) h = 0.0f;
                local += h;
            }
        }
    }
    #pragma unroll
    for (int off = 32; off > 0; off >>= 1) local += __shfl_xor(local, off);
    if (lane == 0) redW[wv] = local;
    __syncthreads();
    if (tid == 0) {
        float s = 0.0f;
        #pragma unroll
        for (int w = 0; w < 8; ++w) s += redW[w];
        atomicAdd(out, s);
    }
}

extern "C" void kernel_launch(void* const* d_in, const int* in_sizes, int n_in,
                              void* d_out, int out_size, void* d_ws, size_t ws_size,
                              hipStream_t stream) {
    const float* X = (const float*)d_in[0];
    const float* Y = (const float*)d_in[1];
    float* out = (float*)d_out;

    unsigned char* Xn = (unsigned char*)d_ws;                        // 4 MB fp4
    unsigned char* Yn = Xn + (size_t)N_ROWS * ROWB;                  // 4 MB fp4
    float* pos = (float*)(Yn + (size_t)N_ROWS * ROWB);               // 32 KB

    hipMemsetAsync(d_out, 0, sizeof(float), stream);
    norm_kernel<<<N_ROWS, 256, 0, stream>>>(X, Y, (unsigned short*)Xn, (unsigned short*)Yn, pos);
    const int ntiles = (N_ROWS / BM) * (N_ROWS / BN);   // 1024
    gemm_loss_kernel<<<dim3(ntiles), 512, 0, stream>>>(Xn, Yn, pos, out);
}